// Round 12
// baseline (890.029 us; speedup 1.0000x reference)
//
#include <hip/hip_runtime.h>

__device__ __forceinline__ float sigf(float x){ return 1.0f/(1.0f+__expf(-x)); }
__device__ __forceinline__ float tanhfast(float x){ return 1.0f - 2.0f/(__expf(2.0f*x)+1.0f); }

#define Bn 16
#define Tn 128
#define Fn 40
#define Hn 64
#define Dn 80   // 2F
#define NHn 5
#define DKn 16
#define FFn 320

#define LD4(p,i) (((const float4*)(p))[i])
// 4 named float4 (16 floats = quarter gate row) — below every granted-VGPR
// ceiling observed in rounds 4-11 (48/148/80/88/52/28).
#define DECL4(v, p) \
  float4 v##0=LD4(p,0), v##1=LD4(p,1), v##2=LD4(p,2), v##3=LD4(p,3);
#define PIN4(P) asm volatile("" : "+v"(P.x), "+v"(P.y), "+v"(P.z), "+v"(P.w));
#define PINW(v) PIN4(v##0) PIN4(v##1) PIN4(v##2) PIN4(v##3)

// dot of 16 weights vs h[jc*16 .. jc*16+16)
#define DOT16(jc4) \
  { const float4 h0=hb4[(jc4)+0]; a += h0.x*w0.x + h0.y*w0.y + h0.z*w0.z + h0.w*w0.w; } \
  { const float4 h1=hb4[(jc4)+1]; a += h1.x*w1.x + h1.y*w1.y + h1.z*w1.z + h1.w*w1.w; } \
  { const float4 h2=hb4[(jc4)+2]; a += h2.x*w2.x + h2.y*w2.y + h2.z*w2.z + h2.w*w2.w; } \
  { const float4 h3=hb4[(jc4)+3]; a += h3.x*w3.x + h3.y*w3.y + h3.z*w3.z + h3.w*w3.w; }

// ---------------- Stage A: per-feature LSTMs (q,k,v) ----------------
// grid 1281 x 1024. blk<640: q inst=blk; <1280: k; ==1280: v lane-parallel.
// 16 waves; lane=(r16, jc): wave covers 16 rows x 4 j-chunks; partials reduced
// in-wave via shfl_xor(16/32); threads<64 do activation and own h,c.
__global__ __launch_bounds__(1024)
void k_feat_lstm6(
    const float* __restrict__ x,
    const float* __restrict__ qWih, const float* __restrict__ qWhh, const float* __restrict__ qb,
    const float* __restrict__ kWih, const float* __restrict__ kWhh, const float* __restrict__ kb,
    const float* __restrict__ vWih, const float* __restrict__ vWhh, const float* __restrict__ vb,
    float* __restrict__ hq, float* __restrict__ hk, float* __restrict__ hv)
{
  const int blk = blockIdx.x;
  const int t = threadIdx.x;
  if (blk >= 1280){
    const int inst = t;                         // 0..1023, guard
    if (inst < 640){
      const int bi = inst/Fn, f = inst%Fn;
      const float* xp = x + bi*Tn*Fn + f;
      const float wih0=vWih[0], wih1=vWih[1], wih2=vWih[2], wih3=vWih[3];
      const float u0v=vWhh[0], u1v=vWhh[1], u2v=vWhh[2], u3v=vWhh[3];
      const float c0=vb[0], c1=vb[1], c2=vb[2], c3=vb[3];
      float h=0.f, c=0.f;
      #pragma unroll 1
      for (int tt=0;tt<Tn;++tt){
        float xt = xp[tt*Fn];
        float zi = xt*wih0 + h*u0v + c0;
        float zf = xt*wih1 + h*u1v + c1;
        float zg = xt*wih2 + h*u2v + c2;
        float zo = xt*wih3 + h*u3v + c3;
        c = sigf(zf)*c + sigf(zi)*tanhfast(zg);
        h = sigf(zo)*tanhfast(c);
      }
      hv[inst] = h;
    }
    return;
  }
  const bool isk = blk >= 640;
  const int inst = isk ? blk-640 : blk;         // 0..639
  const int bi = inst/Fn, f = inst%Fn;
  const float* Whh = isk ? kWhh : qWhh;
  const float* Wih = isk ? kWih : qWih;
  const float* bia = isk ? kb  : qb;
  float* outp = isk ? hk : hq;

  const int lane = t & 63;
  const int wv   = t >> 6;        // 0..15
  const int r16  = lane & 15;
  const int jc   = lane >> 4;     // 0..3
  const int row  = wv*16 + r16;   // 0..255
  const int jc4  = jc*4;

  DECL4(w, Whh + row*Hn + jc*16);
  PINW(w);
  const float wih = Wih[row];
  const float bb  = bia[row];

  __shared__ __align__(16) float hls[Hn];
  __shared__ float zls[4*Hn];
  __shared__ float xls[Tn];

  const float* xp = x + bi*Tn*Fn + f;
  if (t < Tn) xls[t] = xp[t*Fn];
  if (t < Hn) hls[t] = 0.f;
  float c = 0.f, h = 0.f;
  __syncthreads();

  const float4* hb4 = (const float4*)hls;
  #pragma unroll 1
  for (int tt=0;tt<Tn;++tt){
    float a = (jc==0) ? (bb + xls[tt]*wih) : 0.f;
    DOT16(jc4)
    a += __shfl_xor(a, 16);
    a += __shfl_xor(a, 32);
    if (jc==0) zls[row] = a;
    __syncthreads();
    if (t < Hn){
      const float zi = zls[t], zf = zls[t+64], zg = zls[t+128], zo = zls[t+192];
      c = sigf(zf)*c + sigf(zi)*tanhfast(zg);
      h = sigf(zo)*tanhfast(c);
      hls[t] = h;
    }
    __syncthreads();
  }
  if (t < Hn) outp[inst*Hn + t] = h;
}

// ---------------- Stage B1: feature attention softmax (writes output b) ----------------
__global__ __launch_bounds__(64) void k_featattn(
    const float* __restrict__ hq, const float* __restrict__ hk, const float* __restrict__ hv,
    float* __restrict__ Wsm, float* __restrict__ out_b)
{
  const int blk = blockIdx.x;
  const int bi = blk / Fn, i = blk % Fn;
  const int j = threadIdx.x;
  __shared__ float qrow[Hn];
  qrow[j] = hq[blk*Hn + j];
  __syncthreads();
  float s = -1e30f;
  if (j < Fn){
    const float* krow = hk + (bi*Fn + j)*Hn;
    float a = 0.f;
    #pragma unroll
    for (int h2=0; h2<Hn; ++h2) a += qrow[h2]*krow[h2];
    s = a * 0.125f * hv[bi*Fn + j];
  }
  float m = s;
  #pragma unroll
  for (int off=32; off>0; off>>=1) m = fmaxf(m, __shfl_xor(m, off));
  float e = (j < Fn) ? __expf(s - m) : 0.f;
  float tot = e;
  #pragma unroll
  for (int off=32; off>0; off>>=1) tot += __shfl_xor(tot, off);
  float p = e / tot;
  if (j < Fn){
    Wsm[blk*Fn + j] = p;
    out_b[bi*(Fn*Fn) + j*Fn + i] = p;
  }
}

// ---------------- Stage B2: attn_output + src concat ----------------
__global__ __launch_bounds__(128) void k_build_src(
    const float* __restrict__ x, const float* __restrict__ Wsm, float* __restrict__ src)
{
  const int blk = blockIdx.x;
  const int bi = blk / Tn;
  const int tid = threadIdx.x;
  __shared__ float xrow[Fn];
  if (tid < Fn) xrow[tid] = x[blk*Fn + tid];
  __syncthreads();
  if (tid < Fn){
    src[blk*Dn + tid] = xrow[tid];
  } else if (tid < Dn){
    const int i = tid - Fn;
    const float* wrow = Wsm + (bi*Fn + i)*Fn;
    float a = 0.f;
    #pragma unroll
    for (int j2=0;j2<Fn;++j2) a += xrow[j2]*wrow[j2];
    src[blk*Dn + tid] = a;
  }
}

// ---------------- Transformer: qkv projection ----------------
__global__ __launch_bounds__(128) void k_qkv(
    const float* __restrict__ src,
    const float* __restrict__ Wq, const float* __restrict__ bq,
    const float* __restrict__ Wk, const float* __restrict__ bk,
    const float* __restrict__ Wv, const float* __restrict__ bv,
    float* __restrict__ q, float* __restrict__ k, float* __restrict__ v)
{
  const int row = blockIdx.x;
  const int t = threadIdx.x;
  __shared__ float qs[Dn];
  __shared__ float qrow[Dn];
  if (t < Dn) qs[t] = src[row*Dn + (t%5)*16 + t/5];
  __syncthreads();
  if (t < Dn){
    const float* wr = Wq + t*Dn;
    float a = bq[t];
    #pragma unroll 8
    for (int d2=0; d2<Dn; ++d2) a += qs[d2]*wr[d2];
    qrow[t] = a;
    q[row*Dn + t] = a;
  }
  __syncthreads();
  if (t < Dn){
    const float* wk = Wk + t*Dn;
    const float* wv = Wv + t*Dn;
    float ak = bk[t], av = bv[t];
    #pragma unroll 8
    for (int d2=0; d2<Dn; ++d2){ float qq = qrow[d2]; ak += qq*wk[d2]; av += qq*wv[d2]; }
    k[row*Dn + t] = ak;
    v[row*Dn + t] = av;
  }
}

// ---------------- Transformer: attention ----------------
__global__ __launch_bounds__(128) void k_attn(
    const float* __restrict__ q, const float* __restrict__ k, const float* __restrict__ v,
    float* __restrict__ o, float* __restrict__ c_out)
{
  const int s1 = blockIdx.x, h = blockIdx.y, bi = blockIdx.z;
  const int s2 = threadIdx.x;
  __shared__ float qf[DKn];
  __shared__ float p[Tn];
  __shared__ float red_m[2];
  __shared__ float red_s[2];
  if (s2 < DKn) qf[s2] = q[(bi*Tn + s1)*Dn + h*DKn + s2];
  __syncthreads();
  const float* krow = k + (bi*Tn + s2)*Dn + h*DKn;
  float a = 0.f;
  #pragma unroll
  for (int d2=0; d2<DKn; ++d2) a += qf[d2]*krow[d2];
  a *= 0.25f;
  const int wv_id = s2 >> 6;
  float m = a;
  #pragma unroll
  for (int off=32; off>0; off>>=1) m = fmaxf(m, __shfl_xor(m, off));
  if ((s2 & 63) == 0) red_m[wv_id] = m;
  __syncthreads();
  m = fmaxf(red_m[0], red_m[1]);
  float e = __expf(a - m);
  float tot = e;
  #pragma unroll
  for (int off=32; off>0; off>>=1) tot += __shfl_xor(tot, off);
  if ((s2 & 63) == 0) red_s[wv_id] = tot;
  __syncthreads();
  tot = red_s[0] + red_s[1];
  float pv = e / tot;
  p[s2] = pv;
  c_out[((bi*NHn + h)*Tn + s1)*Tn + s2] = pv;
  __syncthreads();
  if (s2 < DKn){
    const float* vcol = v + bi*Tn*Dn + h*DKn + s2;
    float acc = 0.f;
    for (int j2=0;j2<Tn;++j2) acc += p[j2]*vcol[j2*Dn];
    o[(bi*Tn + s1)*Dn + h*DKn + s2] = acc;
  }
}

// ---------------- Transformer: fused (Wo+res+LN) -> (FF+res+LN), row-local ----------------
__global__ __launch_bounds__(320) void k_oln_ffln(
    const float* __restrict__ o, const float* __restrict__ Wo, const float* __restrict__ bo,
    const float* __restrict__ W1, const float* __restrict__ b1,
    const float* __restrict__ W2, const float* __restrict__ b2,
    const float* __restrict__ lng, const float* __restrict__ lnb, float* __restrict__ src)
{
  const int row = blockIdx.x;
  const int t = threadIdx.x;
  __shared__ float orow[Dn];
  __shared__ float s1row[Dn];
  __shared__ float h1[FFn];
  __shared__ float red[128];
  if (t < Dn) orow[t] = o[row*Dn + t];
  __syncthreads();
  float val = 0.f;
  if (t < Dn){
    const float* wr = Wo + t*Dn;
    float a = bo[t];
    #pragma unroll 8
    for (int d2=0; d2<Dn; ++d2) a += orow[d2]*wr[d2];
    val = a + src[row*Dn + t];
  }
  if (t < 128) red[t] = (t < Dn) ? val : 0.f;
  __syncthreads();
  for (int s=64; s>0; s>>=1){ if (t < s) red[t] += red[t+s]; __syncthreads(); }
  float mean = red[0] * (1.f/Dn);
  __syncthreads();
  if (t < 128){ float dv = (t < Dn) ? (val - mean) : 0.f; red[t] = dv*dv; }
  __syncthreads();
  for (int s=64; s>0; s>>=1){ if (t < s) red[t] += red[t+s]; __syncthreads(); }
  float rstd = rsqrtf(red[0]*(1.f/Dn) + 1e-5f);
  if (t < Dn) s1row[t] = (val - mean)*rstd*lng[t] + lnb[t];
  __syncthreads();
  {
    const float* wr = W1 + t*Dn;
    float a = b1[t];
    #pragma unroll 8
    for (int d2=0; d2<Dn; ++d2) a += s1row[d2]*wr[d2];
    h1[t] = fmaxf(a, 0.f);
  }
  __syncthreads();
  float val2 = 0.f;
  if (t < Dn){
    const float* wr = W2 + t*FFn;
    float a = b2[t];
    #pragma unroll 8
    for (int d2=0; d2<FFn; ++d2) a += h1[d2]*wr[d2];
    val2 = a + s1row[t];
  }
  if (t < 128) red[t] = (t < Dn) ? val2 : 0.f;
  __syncthreads();
  for (int s=64; s>0; s>>=1){ if (t < s) red[t] += red[t+s]; __syncthreads(); }
  mean = red[0] * (1.f/Dn);
  __syncthreads();
  if (t < 128){ float dv = (t < Dn) ? (val2 - mean) : 0.f; red[t] = dv*dv; }
  __syncthreads();
  for (int s=64; s>0; s>>=1){ if (t < s) red[t] += red[t+s]; __syncthreads(); }
  rstd = rsqrtf(red[0]*(1.f/Dn) + 1e-5f);
  if (t < Dn) src[row*Dn + t] = (val2 - mean)*rstd*lng[t] + lnb[t];
}

// ---------------- BiLSTM: parallel input projection gx = X @ Wih.T + b ----------------
__global__ __launch_bounds__(256) void k_gx(
    const float* __restrict__ X, int inD,
    const float* __restrict__ WihF, const float* __restrict__ bF,
    const float* __restrict__ WihB, const float* __restrict__ bB,
    float* __restrict__ gx)
{
  const int row = blockIdx.x;
  const int dir = blockIdx.y;
  const int g = threadIdx.x;
  __shared__ float xs[128];
  for (int d2=g; d2<inD; d2+=256) xs[d2] = X[row*inD + d2];
  __syncthreads();
  const float* W  = dir ? WihB : WihF;
  const float* bb = dir ? bB  : bF;
  const float* wr = W + g*inD;
  float a = bb[g];
  for (int d2=0; d2<inD; ++d2) a += xs[d2]*wr[d2];
  gx[dir*(Bn*Tn*256) + row*256 + g] = a;
}

// ---------------- BiLSTM recurrence: 1024 thr, in-wave j-split x4 ----------------
// grid (16,2), block 1024. out[n,t, dir*64 + l]
__global__ __launch_bounds__(1024)
void k_bilstm_rec6(
    const float* __restrict__ gx,
    const float* __restrict__ WhhF, const float* __restrict__ WhhB,
    float* __restrict__ outp)
{
  const int n = blockIdx.x;
  const int dir = blockIdx.y;
  const int t = threadIdx.x;
  const int lane = t & 63;
  const int wv   = t >> 6;
  const int r16  = lane & 15;
  const int jc   = lane >> 4;
  const int row  = wv*16 + r16;
  const int jc4  = jc*4;
  const float* Whh = dir ? WhhB : WhhF;
  DECL4(w, Whh + row*Hn + jc*16);
  PINW(w);

  __shared__ __align__(16) float hls[Hn];
  __shared__ float zls[4*Hn];
  if (t < Hn) hls[t] = 0.f;
  float c = 0.f, h = 0.f;
  __syncthreads();

  const float* gxd = gx + dir*(Bn*Tn*256) + n*Tn*256;
  const float4* hb4 = (const float4*)hls;
  const int t0 = dir ? Tn-1 : 0;
  float g0 = (jc==0) ? gxd[t0*256 + row] : 0.f;
  #pragma unroll 1
  for (int step=0; step<Tn; ++step){
    const int tt = dir ? (Tn-1-step) : step;
    int tn = dir ? (Tn-2-step) : (step+1);
    tn = max(0, min(Tn-1, tn));
    const float p0 = (jc==0) ? gxd[tn*256 + row] : 0.f;   // prefetch next
    float a = g0;
    DOT16(jc4)
    a += __shfl_xor(a, 16);
    a += __shfl_xor(a, 32);
    if (jc==0) zls[row] = a;
    __syncthreads();
    if (t < Hn){
      const float zi = zls[t], zf = zls[t+64], zg = zls[t+128], zo = zls[t+192];
      c = sigf(zf)*c + sigf(zi)*tanhfast(zg);
      h = sigf(zo)*tanhfast(c);
      hls[t] = h;
      outp[(n*Tn + tt)*128 + dir*Hn + t] = h;
    }
    __syncthreads();
    g0 = p0;
  }
}

// ---------------- Final head ----------------
__global__ __launch_bounds__(128) void k_final(
    const float* __restrict__ out1,
    const float* __restrict__ fc1W, const float* __restrict__ fc1b,
    const float* __restrict__ fc2W, const float* __restrict__ fc2b,
    float* __restrict__ outp)
{
  const int n = blockIdx.x;
  const int t = threadIdx.x;
  __shared__ float r[128];
  __shared__ float a1[64];
  r[t] = fmaxf(out1[(n*Tn + (Tn-1))*128 + t], 0.f);
  __syncthreads();
  if (t < 64){
    const float* wr = fc1W + t*128;
    float a = fc1b[t];
    #pragma unroll 8
    for (int d2=0; d2<128; ++d2) a += r[d2]*wr[d2];
    a1[t] = fmaxf(a, 0.f);
  }
  __syncthreads();
  if (t == 0){
    float a = fc2b[0];
    #pragma unroll 8
    for (int d2=0; d2<64; ++d2) a += a1[d2]*fc2W[d2];
    outp[n] = a;
  }
}

extern "C" void kernel_launch(void* const* d_in, const int* in_sizes, int n_in,
                              void* d_out, int out_size, void* d_ws, size_t ws_size,
                              hipStream_t stream)
{
  const float* x     = (const float*)d_in[0];
  const float* qWih  = (const float*)d_in[1];
  const float* qWhh  = (const float*)d_in[2];
  const float* qb    = (const float*)d_in[3];
  const float* kWih  = (const float*)d_in[4];
  const float* kWhh  = (const float*)d_in[5];
  const float* kb    = (const float*)d_in[6];
  const float* vWih  = (const float*)d_in[7];
  const float* vWhh  = (const float*)d_in[8];
  const float* vb    = (const float*)d_in[9];
  const float* tWq   = (const float*)d_in[10];
  const float* tbq   = (const float*)d_in[11];
  const float* tWk   = (const float*)d_in[12];
  const float* tbk   = (const float*)d_in[13];
  const float* tWv   = (const float*)d_in[14];
  const float* tbv   = (const float*)d_in[15];
  const float* tWo   = (const float*)d_in[16];
  const float* tbo   = (const float*)d_in[17];
  const float* tW1   = (const float*)d_in[18];
  const float* tb1   = (const float*)d_in[19];
  const float* tW2   = (const float*)d_in[20];
  const float* tb2   = (const float*)d_in[21];
  const float* tlng  = (const float*)d_in[22];
  const float* tlnb  = (const float*)d_in[23];
  const float* l0fWih= (const float*)d_in[24];
  const float* l0fWhh= (const float*)d_in[25];
  const float* l0fb  = (const float*)d_in[26];
  const float* l0bWih= (const float*)d_in[27];
  const float* l0bWhh= (const float*)d_in[28];
  const float* l0bb  = (const float*)d_in[29];
  const float* l1fWih= (const float*)d_in[30];
  const float* l1fWhh= (const float*)d_in[31];
  const float* l1fb  = (const float*)d_in[32];
  const float* l1bWih= (const float*)d_in[33];
  const float* l1bWhh= (const float*)d_in[34];
  const float* l1bb  = (const float*)d_in[35];
  const float* fc1W  = (const float*)d_in[36];
  const float* fc1b  = (const float*)d_in[37];
  const float* fc2W  = (const float*)d_in[38];
  const float* fc2b  = (const float*)d_in[39];

  float* ws  = (float*)d_ws;
  float* hq  = ws;
  float* hk  = hq  + 640*64;
  float* hv  = hk  + 640*64;
  float* Wsm = hv  + 640;
  float* src = Wsm + 16*40*40;
  float* q   = src + 16*128*80;
  float* k   = q   + 16*128*80;
  float* v   = k   + 16*128*80;
  float* o   = v   + 16*128*80;
  float* gx  = o   + 16*128*80;
  float* lout0 = gx + 2*16*128*256;
  float* lout1 = lout0 + 16*128*128;

  float* outp  = (float*)d_out;
  float* out_b = outp + 16;
  float* out_c = out_b + 16*40*40;

  k_feat_lstm6<<<1281, 1024, 0, stream>>>(x, qWih,qWhh,qb, kWih,kWhh,kb, vWih,vWhh,vb, hq,hk,hv);
  k_featattn<<<640, 64, 0, stream>>>(hq, hk, hv, Wsm, out_b);
  k_build_src<<<2048, 128, 0, stream>>>(x, Wsm, src);
  for (int l=0; l<2; ++l){
    k_qkv<<<2048, 128, 0, stream>>>(src, tWq + l*Dn*Dn, tbq + l*Dn,
                                    tWk + l*Dn*Dn, tbk + l*Dn,
                                    tWv + l*Dn*Dn, tbv + l*Dn, q, k, v);
    k_attn<<<dim3(128,5,16), 128, 0, stream>>>(q, k, v, o, out_c + (size_t)l*16*5*128*128);
    k_oln_ffln<<<2048, 320, 0, stream>>>(o, tWo + l*Dn*Dn, tbo + l*Dn,
                                         tW1 + l*FFn*Dn, tb1 + l*FFn,
                                         tW2 + l*Dn*FFn, tb2 + l*Dn,
                                         tlng + l*Dn, tlnb + l*Dn, src);
  }
  k_gx<<<dim3(2048,2), 256, 0, stream>>>(src, 80, l0fWih, l0fb, l0bWih, l0bb, gx);
  k_bilstm_rec6<<<dim3(16,2), 1024, 0, stream>>>(gx, l0fWhh, l0bWhh, lout0);
  k_gx<<<dim3(2048,2), 256, 0, stream>>>(lout0, 128, l1fWih, l1fb, l1bWih, l1bb, gx);
  k_bilstm_rec6<<<dim3(16,2), 1024, 0, stream>>>(gx, l1fWhh, l1bWhh, lout1);
  k_final<<<16, 128, 0, stream>>>(lout1, fc1W, fc1b, fc2W, fc2b, outp);
}

// Round 13
// 663.091 us; speedup vs baseline: 1.3422x; 1.3422x over previous
//
#include <hip/hip_runtime.h>

__device__ __forceinline__ float sigf(float x){ return 1.0f/(1.0f+__expf(-x)); }
__device__ __forceinline__ float tanhfast(float x){ return 1.0f - 2.0f/(__expf(2.0f*x)+1.0f); }

#define Bn 16
#define Tn 128
#define Fn 40
#define Hn 64
#define Dn 80   // 2F
#define NHn 5
#define DKn 16
#define FFn 320

// ---- round-6 macro (proven best feat config) ----
#define LOAD_PIN_ROW(dst, srcp)                                        \
  {                                                                    \
    _Pragma("unroll")                                                  \
    for (int jj=0; jj<16; ++jj){                                       \
      float4 tv = *(const float4*)((srcp) + 4*jj);                     \
      dst[4*jj]=tv.x; dst[4*jj+1]=tv.y; dst[4*jj+2]=tv.z; dst[4*jj+3]=tv.w; \
    }                                                                  \
    _Pragma("unroll")                                                  \
    for (int jj=0; jj<64; ++jj){ asm volatile("" : "+v"(dst[jj])); }   \
  }

// ---- round-11 macros (rec5) ----
#define LD4(p,i) (((const float4*)(p))[i])
#define DECL8(v, p) \
  float4 v##0=LD4(p,0), v##1=LD4(p,1), v##2=LD4(p,2), v##3=LD4(p,3), \
         v##4=LD4(p,4), v##5=LD4(p,5), v##6=LD4(p,6), v##7=LD4(p,7);
#define PIN4(P) asm volatile("" : "+v"(P.x), "+v"(P.y), "+v"(P.z), "+v"(P.w));
#define PIN8(v) PIN4(v##0) PIN4(v##1) PIN4(v##2) PIN4(v##3) PIN4(v##4) PIN4(v##5) \
  PIN4(v##6) PIN4(v##7)
#define ACC8(base) \
  { const float4 h0=hb4[(base)+0]; a += h0.x*w0.x + h0.y*w0.y + h0.z*w0.z + h0.w*w0.w; } \
  { const float4 h1=hb4[(base)+1]; a += h1.x*w1.x + h1.y*w1.y + h1.z*w1.z + h1.w*w1.w; } \
  { const float4 h2=hb4[(base)+2]; a += h2.x*w2.x + h2.y*w2.y + h2.z*w2.z + h2.w*w2.w; } \
  { const float4 h3=hb4[(base)+3]; a += h3.x*w3.x + h3.y*w3.y + h3.z*w3.z + h3.w*w3.w; } \
  { const float4 h4=hb4[(base)+4]; a += h4.x*w4.x + h4.y*w4.y + h4.z*w4.z + h4.w*w4.w; } \
  { const float4 h5=hb4[(base)+5]; a += h5.x*w5.x + h5.y*w5.y + h5.z*w5.z + h5.w*w5.w; } \
  { const float4 h6=hb4[(base)+6]; a += h6.x*w6.x + h6.y*w6.y + h6.z*w6.z + h6.w*w6.w; } \
  { const float4 h7=hb4[(base)+7]; a += h7.x*w7.x + h7.y*w7.y + h7.z*w7.z + h7.w*w7.w; }

// ---------------- Stage A: per-feature LSTMs (round-6 proven config) ----------------
// grid 1285 x 128. 2-wave block, thread l handles gate rows {l, l+128}; threads<64 own h,c.
__global__ __launch_bounds__(128,1) void k_feat_lstm2(
    const float* __restrict__ x,
    const float* __restrict__ qWih, const float* __restrict__ qWhh, const float* __restrict__ qb,
    const float* __restrict__ kWih, const float* __restrict__ kWhh, const float* __restrict__ kb,
    const float* __restrict__ vWih, const float* __restrict__ vWhh, const float* __restrict__ vb,
    float* __restrict__ hq, float* __restrict__ hk, float* __restrict__ hv)
{
  const int blk = blockIdx.x;
  const int l = threadIdx.x;
  if (blk >= 1280){
    const int inst = (blk - 1280)*128 + l;      // 0..639
    const int bi = inst/Fn, f = inst%Fn;
    const float* xp = x + bi*Tn*Fn + f;
    const float wih0=vWih[0], wih1=vWih[1], wih2=vWih[2], wih3=vWih[3];
    const float u0=vWhh[0], u1=vWhh[1], u2=vWhh[2], u3=vWhh[3];
    const float c0=vb[0], c1=vb[1], c2=vb[2], c3=vb[3];
    float h=0.f, c=0.f;
    #pragma unroll 1
    for (int t=0;t<Tn;++t){
      float xt = xp[t*Fn];
      float zi = xt*wih0 + h*u0 + c0;
      float zf = xt*wih1 + h*u1 + c1;
      float zg = xt*wih2 + h*u2 + c2;
      float zo = xt*wih3 + h*u3 + c3;
      c = sigf(zf)*c + sigf(zi)*tanhfast(zg);
      h = sigf(zo)*tanhfast(c);
    }
    hv[inst] = h;
    return;
  }
  const bool isk = blk >= 640;
  const int inst = isk ? blk-640 : blk;         // 0..639
  const int bi = inst/Fn, f = inst%Fn;
  const float* Whh = isk ? kWhh : qWhh;
  const float* Wih = isk ? kWih : qWih;
  const float* bia = isk ? kb  : qb;
  float* outp = isk ? hk : hq;

  const int r0 = l;        // i (l<64) or f (l>=64)
  const int r1 = l + 128;  // g (l<64) or o (l>=64)

  float w0[Hn], w1[Hn];
  LOAD_PIN_ROW(w0, Whh + r0*Hn);
  LOAD_PIN_ROW(w1, Whh + r1*Hn);
  const float wih0 = Wih[r0], wih1 = Wih[r1];
  const float bb0 = bia[r0], bb1 = bia[r1];

  __shared__ __align__(16) float hb[Hn];
  __shared__ float zb[4*Hn];
  __shared__ float xls[Tn];

  const float* xp = x + bi*Tn*Fn + f;
  xls[l] = xp[l*Fn];                    // stage all 128 timesteps
  if (l < Hn) hb[l] = 0.f;
  float c = 0.f, h = 0.f;
  __syncthreads();

  const float4* hb4 = (const float4*)hb;
  #pragma unroll 1
  for (int t=0;t<Tn;++t){
    const float xt = xls[t];
    float a0 = bb0 + xt*wih0;
    float a1 = bb1 + xt*wih1;
    #pragma unroll
    for (int jj=0; jj<16; ++jj){
      const float4 hv4 = hb4[jj];
      a0 += hv4.x*w0[4*jj  ] + hv4.y*w0[4*jj+1] + hv4.z*w0[4*jj+2] + hv4.w*w0[4*jj+3];
      a1 += hv4.x*w1[4*jj  ] + hv4.y*w1[4*jj+1] + hv4.z*w1[4*jj+2] + hv4.w*w1[4*jj+3];
    }
    if (l >= Hn){ zb[l] = a0; zb[l+128] = a1; }   // f-row, o-row
    __syncthreads();
    if (l < Hn){
      const float zi = a0, zg = a1;
      const float zf = zb[l+64], zo = zb[l+192];
      c = sigf(zf)*c + sigf(zi)*tanhfast(zg);
      h = sigf(zo)*tanhfast(c);
      hb[l] = h;
    }
    __syncthreads();
  }
  if (l < Hn) outp[inst*Hn + l] = h;
}

// ---------------- Stage B1: feature attention softmax (writes output b) ----------------
__global__ __launch_bounds__(64) void k_featattn(
    const float* __restrict__ hq, const float* __restrict__ hk, const float* __restrict__ hv,
    float* __restrict__ Wsm, float* __restrict__ out_b)
{
  const int blk = blockIdx.x;
  const int bi = blk / Fn, i = blk % Fn;
  const int j = threadIdx.x;
  __shared__ float qrow[Hn];
  qrow[j] = hq[blk*Hn + j];
  __syncthreads();
  float s = -1e30f;
  if (j < Fn){
    const float* krow = hk + (bi*Fn + j)*Hn;
    float a = 0.f;
    #pragma unroll
    for (int h2=0; h2<Hn; ++h2) a += qrow[h2]*krow[h2];
    s = a * 0.125f * hv[bi*Fn + j];
  }
  float m = s;
  #pragma unroll
  for (int off=32; off>0; off>>=1) m = fmaxf(m, __shfl_xor(m, off));
  float e = (j < Fn) ? __expf(s - m) : 0.f;
  float tot = e;
  #pragma unroll
  for (int off=32; off>0; off>>=1) tot += __shfl_xor(tot, off);
  float p = e / tot;
  if (j < Fn){
    Wsm[blk*Fn + j] = p;
    out_b[bi*(Fn*Fn) + j*Fn + i] = p;
  }
}

// ---------------- Stage B2: attn_output + src concat ----------------
__global__ __launch_bounds__(128) void k_build_src(
    const float* __restrict__ x, const float* __restrict__ Wsm, float* __restrict__ src)
{
  const int blk = blockIdx.x;
  const int bi = blk / Tn;
  const int tid = threadIdx.x;
  __shared__ float xrow[Fn];
  if (tid < Fn) xrow[tid] = x[blk*Fn + tid];
  __syncthreads();
  if (tid < Fn){
    src[blk*Dn + tid] = xrow[tid];
  } else if (tid < Dn){
    const int i = tid - Fn;
    const float* wrow = Wsm + (bi*Fn + i)*Fn;
    float a = 0.f;
    #pragma unroll
    for (int j2=0;j2<Fn;++j2) a += xrow[j2]*wrow[j2];
    src[blk*Dn + tid] = a;
  }
}

// ---------------- Transformer: qkv projection ----------------
__global__ __launch_bounds__(128) void k_qkv(
    const float* __restrict__ src,
    const float* __restrict__ Wq, const float* __restrict__ bq,
    const float* __restrict__ Wk, const float* __restrict__ bk,
    const float* __restrict__ Wv, const float* __restrict__ bv,
    float* __restrict__ q, float* __restrict__ k, float* __restrict__ v)
{
  const int row = blockIdx.x;
  const int t = threadIdx.x;
  __shared__ float qs[Dn];
  __shared__ float qrow[Dn];
  if (t < Dn) qs[t] = src[row*Dn + (t%5)*16 + t/5];
  __syncthreads();
  if (t < Dn){
    const float* wr = Wq + t*Dn;
    float a = bq[t];
    #pragma unroll 8
    for (int d2=0; d2<Dn; ++d2) a += qs[d2]*wr[d2];
    qrow[t] = a;
    q[row*Dn + t] = a;
  }
  __syncthreads();
  if (t < Dn){
    const float* wk = Wk + t*Dn;
    const float* wv = Wv + t*Dn;
    float ak = bk[t], av = bv[t];
    #pragma unroll 8
    for (int d2=0; d2<Dn; ++d2){ float qq = qrow[d2]; ak += qq*wk[d2]; av += qq*wv[d2]; }
    k[row*Dn + t] = ak;
    v[row*Dn + t] = av;
  }
}

// ---------------- Transformer: attention (PV parallelized over 128 threads) ----------------
__global__ __launch_bounds__(128) void k_attn(
    const float* __restrict__ q, const float* __restrict__ k, const float* __restrict__ v,
    float* __restrict__ o, float* __restrict__ c_out)
{
  const int s1 = blockIdx.x, h = blockIdx.y, bi = blockIdx.z;
  const int s2 = threadIdx.x;
  __shared__ float qf[DKn];
  __shared__ float p[Tn];
  __shared__ float pa[128];
  __shared__ float red_m[2];
  __shared__ float red_s[2];
  if (s2 < DKn) qf[s2] = q[(bi*Tn + s1)*Dn + h*DKn + s2];
  __syncthreads();
  const float* krow = k + (bi*Tn + s2)*Dn + h*DKn;
  float a = 0.f;
  #pragma unroll
  for (int d2=0; d2<DKn; ++d2) a += qf[d2]*krow[d2];
  a *= 0.25f;
  const int wv_id = s2 >> 6;
  float m = a;
  #pragma unroll
  for (int off=32; off>0; off>>=1) m = fmaxf(m, __shfl_xor(m, off));
  if ((s2 & 63) == 0) red_m[wv_id] = m;
  __syncthreads();
  m = fmaxf(red_m[0], red_m[1]);
  float e = __expf(a - m);
  float tot = e;
  #pragma unroll
  for (int off=32; off>0; off>>=1) tot += __shfl_xor(tot, off);
  if ((s2 & 63) == 0) red_s[wv_id] = tot;
  __syncthreads();
  tot = red_s[0] + red_s[1];
  float pv = e / tot;
  p[s2] = pv;
  c_out[((bi*NHn + h)*Tn + s1)*Tn + s2] = pv;
  __syncthreads();
  // PV: thread = (part 0..7, d 0..15); each accumulates 16 j's
  {
    const int d    = s2 & 15;
    const int part = s2 >> 4;
    const float* vcol = v + bi*Tn*Dn + h*DKn + d;
    float acc = 0.f;
    #pragma unroll
    for (int jj=0; jj<16; ++jj){
      const int j2 = part*16 + jj;
      acc += p[j2]*vcol[j2*Dn];
    }
    pa[s2] = acc;
  }
  __syncthreads();
  if (s2 < DKn){
    float acc = 0.f;
    #pragma unroll
    for (int k2=0; k2<8; ++k2) acc += pa[k2*16 + s2];
    o[(bi*Tn + s1)*Dn + h*DKn + s2] = acc;
  }
}

// ---------------- Transformer: fused (Wo+res+LN) -> (FF+res+LN), row-local ----------------
__global__ __launch_bounds__(320) void k_oln_ffln(
    const float* __restrict__ o, const float* __restrict__ Wo, const float* __restrict__ bo,
    const float* __restrict__ W1, const float* __restrict__ b1,
    const float* __restrict__ W2, const float* __restrict__ b2,
    const float* __restrict__ lng, const float* __restrict__ lnb, float* __restrict__ src)
{
  const int row = blockIdx.x;
  const int t = threadIdx.x;
  __shared__ float orow[Dn];
  __shared__ float s1row[Dn];
  __shared__ float h1[FFn];
  __shared__ float red[128];
  if (t < Dn) orow[t] = o[row*Dn + t];
  __syncthreads();
  float val = 0.f;
  if (t < Dn){
    const float* wr = Wo + t*Dn;
    float a = bo[t];
    #pragma unroll 8
    for (int d2=0; d2<Dn; ++d2) a += orow[d2]*wr[d2];
    val = a + src[row*Dn + t];
  }
  if (t < 128) red[t] = (t < Dn) ? val : 0.f;
  __syncthreads();
  for (int s=64; s>0; s>>=1){ if (t < s) red[t] += red[t+s]; __syncthreads(); }
  float mean = red[0] * (1.f/Dn);
  __syncthreads();
  if (t < 128){ float dv = (t < Dn) ? (val - mean) : 0.f; red[t] = dv*dv; }
  __syncthreads();
  for (int s=64; s>0; s>>=1){ if (t < s) red[t] += red[t+s]; __syncthreads(); }
  float rstd = rsqrtf(red[0]*(1.f/Dn) + 1e-5f);
  if (t < Dn) s1row[t] = (val - mean)*rstd*lng[t] + lnb[t];
  __syncthreads();
  {
    const float* wr = W1 + t*Dn;
    float a = b1[t];
    #pragma unroll 8
    for (int d2=0; d2<Dn; ++d2) a += s1row[d2]*wr[d2];
    h1[t] = fmaxf(a, 0.f);
  }
  __syncthreads();
  float val2 = 0.f;
  if (t < Dn){
    const float* wr = W2 + t*FFn;
    float a = b2[t];
    #pragma unroll 8
    for (int d2=0; d2<FFn; ++d2) a += h1[d2]*wr[d2];
    val2 = a + s1row[t];
  }
  if (t < 128) red[t] = (t < Dn) ? val2 : 0.f;
  __syncthreads();
  for (int s=64; s>0; s>>=1){ if (t < s) red[t] += red[t+s]; __syncthreads(); }
  mean = red[0] * (1.f/Dn);
  __syncthreads();
  if (t < 128){ float dv = (t < Dn) ? (val2 - mean) : 0.f; red[t] = dv*dv; }
  __syncthreads();
  for (int s=64; s>0; s>>=1){ if (t < s) red[t] += red[t+s]; __syncthreads(); }
  rstd = rsqrtf(red[0]*(1.f/Dn) + 1e-5f);
  if (t < Dn) src[row*Dn + t] = (val2 - mean)*rstd*lng[t] + lnb[t];
}

// ---------------- BiLSTM gx: 8 timesteps/block, weight read amortized 8x ----------------
// grid (256, 2), block 256. gx[dir][row*256 + g]
template<int IND>
__global__ __launch_bounds__(256) void k_gx8(
    const float* __restrict__ X,
    const float* __restrict__ WihF, const float* __restrict__ bF,
    const float* __restrict__ WihB, const float* __restrict__ bB,
    float* __restrict__ gx)
{
  const int row0 = blockIdx.x * 8;
  const int dir = blockIdx.y;
  const int g = threadIdx.x;
  __shared__ float xs[8][IND];
  #pragma unroll
  for (int rr=0; rr<8; ++rr)
    for (int d2=g; d2<IND; d2+=256) xs[rr][d2] = X[(row0+rr)*IND + d2];
  __syncthreads();
  const float* W  = dir ? WihB : WihF;
  const float* bb = dir ? bB  : bF;
  const float* wr = W + g*IND;
  float acc[8];
  const float b0 = bb[g];
  #pragma unroll
  for (int rr=0; rr<8; ++rr) acc[rr] = b0;
  #pragma unroll 4
  for (int d2=0; d2<IND; d2+=4){
    const float4 wv = *(const float4*)(wr + d2);
    #pragma unroll
    for (int rr=0; rr<8; ++rr){
      acc[rr] += xs[rr][d2]*wv.x + xs[rr][d2+1]*wv.y + xs[rr][d2+2]*wv.z + xs[rr][d2+3]*wv.w;
    }
  }
  float* gxd = gx + dir*(Bn*Tn*256);
  #pragma unroll
  for (int rr=0; rr<8; ++rr) gxd[(row0+rr)*256 + g] = acc[rr];
}

// ---------------- BiLSTM recurrence (round-11 rec5) ----------------
__global__ __launch_bounds__(512)
void k_bilstm_rec5(
    const float* __restrict__ gx,
    const float* __restrict__ WhhF, const float* __restrict__ WhhB,
    float* __restrict__ outp)
{
  const int n = blockIdx.x;
  const int dir = blockIdx.y;
  const int t = threadIdx.x;
  const int half = t >> 8;
  const int r    = t & 255;
  const float* Whh = dir ? WhhB : WhhF;
  DECL8(w, Whh + r*Hn + half*32);
  PIN8(w);

  __shared__ __align__(16) float hb[Hn];
  __shared__ float pa[512];
  if (t < Hn) hb[t] = 0.f;
  float c = 0.f, h = 0.f;
  __syncthreads();

  const float* gxd = gx + dir*(Bn*Tn*256) + n*Tn*256;
  const float4* hb4 = (const float4*)hb;
  const int jbase = half*8;
  const int t0 = dir ? Tn-1 : 0;
  float g0 = half ? 0.f : gxd[t0*256 + r];
  #pragma unroll 1
  for (int step=0; step<Tn; ++step){
    const int tt = dir ? (Tn-1-step) : step;
    int tn = dir ? (Tn-2-step) : (step+1);
    tn = max(0, min(Tn-1, tn));
    const float p0 = half ? 0.f : gxd[tn*256 + r];   // prefetch next step
    float a = g0;
    ACC8(jbase)
    pa[t] = a;
    __syncthreads();
    if (t < Hn){
      const float zi = pa[t    ] + pa[t+256];
      const float zf = pa[t+ 64] + pa[t+320];
      const float zg = pa[t+128] + pa[t+384];
      const float zo = pa[t+192] + pa[t+448];
      c = sigf(zf)*c + sigf(zi)*tanhfast(zg);
      h = sigf(zo)*tanhfast(c);
      hb[t] = h;
      outp[(n*Tn + tt)*128 + dir*Hn + t] = h;
    }
    __syncthreads();
    g0 = p0;
  }
}

// ---------------- Final head ----------------
__global__ __launch_bounds__(128) void k_final(
    const float* __restrict__ out1,
    const float* __restrict__ fc1W, const float* __restrict__ fc1b,
    const float* __restrict__ fc2W, const float* __restrict__ fc2b,
    float* __restrict__ outp)
{
  const int n = blockIdx.x;
  const int t = threadIdx.x;
  __shared__ float r[128];
  __shared__ float a1[64];
  r[t] = fmaxf(out1[(n*Tn + (Tn-1))*128 + t], 0.f);
  __syncthreads();
  if (t < 64){
    const float* wr = fc1W + t*128;
    float a = fc1b[t];
    #pragma unroll 8
    for (int d2=0; d2<128; ++d2) a += r[d2]*wr[d2];
    a1[t] = fmaxf(a, 0.f);
  }
  __syncthreads();
  if (t == 0){
    float a = fc2b[0];
    #pragma unroll 8
    for (int d2=0; d2<64; ++d2) a += a1[d2]*fc2W[d2];
    outp[n] = a;
  }
}

extern "C" void kernel_launch(void* const* d_in, const int* in_sizes, int n_in,
                              void* d_out, int out_size, void* d_ws, size_t ws_size,
                              hipStream_t stream)
{
  const float* x     = (const float*)d_in[0];
  const float* qWih  = (const float*)d_in[1];
  const float* qWhh  = (const float*)d_in[2];
  const float* qb    = (const float*)d_in[3];
  const float* kWih  = (const float*)d_in[4];
  const float* kWhh  = (const float*)d_in[5];
  const float* kb    = (const float*)d_in[6];
  const float* vWih  = (const float*)d_in[7];
  const float* vWhh  = (const float*)d_in[8];
  const float* vb    = (const float*)d_in[9];
  const float* tWq   = (const float*)d_in[10];
  const float* tbq   = (const float*)d_in[11];
  const float* tWk   = (const float*)d_in[12];
  const float* tbk   = (const float*)d_in[13];
  const float* tWv   = (const float*)d_in[14];
  const float* tbv   = (const float*)d_in[15];
  const float* tWo   = (const float*)d_in[16];
  const float* tbo   = (const float*)d_in[17];
  const float* tW1   = (const float*)d_in[18];
  const float* tb1   = (const float*)d_in[19];
  const float* tW2   = (const float*)d_in[20];
  const float* tb2   = (const float*)d_in[21];
  const float* tlng  = (const float*)d_in[22];
  const float* tlnb  = (const float*)d_in[23];
  const float* l0fWih= (const float*)d_in[24];
  const float* l0fWhh= (const float*)d_in[25];
  const float* l0fb  = (const float*)d_in[26];
  const float* l0bWih= (const float*)d_in[27];
  const float* l0bWhh= (const float*)d_in[28];
  const float* l0bb  = (const float*)d_in[29];
  const float* l1fWih= (const float*)d_in[30];
  const float* l1fWhh= (const float*)d_in[31];
  const float* l1fb  = (const float*)d_in[32];
  const float* l1bWih= (const float*)d_in[33];
  const float* l1bWhh= (const float*)d_in[34];
  const float* l1bb  = (const float*)d_in[35];
  const float* fc1W  = (const float*)d_in[36];
  const float* fc1b  = (const float*)d_in[37];
  const float* fc2W  = (const float*)d_in[38];
  const float* fc2b  = (const float*)d_in[39];

  float* ws  = (float*)d_ws;
  float* hq  = ws;
  float* hk  = hq  + 640*64;
  float* hv  = hk  + 640*64;
  float* Wsm = hv  + 640;
  float* src = Wsm + 16*40*40;
  float* q   = src + 16*128*80;
  float* k   = q   + 16*128*80;
  float* v   = k   + 16*128*80;
  float* o   = v   + 16*128*80;
  float* gx  = o   + 16*128*80;
  float* lout0 = gx + 2*16*128*256;
  float* lout1 = lout0 + 16*128*128;

  float* outp  = (float*)d_out;
  float* out_b = outp + 16;
  float* out_c = out_b + 16*40*40;

  k_feat_lstm2<<<1285, 128, 0, stream>>>(x, qWih,qWhh,qb, kWih,kWhh,kb, vWih,vWhh,vb, hq,hk,hv);
  k_featattn<<<640, 64, 0, stream>>>(hq, hk, hv, Wsm, out_b);
  k_build_src<<<2048, 128, 0, stream>>>(x, Wsm, src);
  for (int l=0; l<2; ++l){
    k_qkv<<<2048, 128, 0, stream>>>(src, tWq + l*Dn*Dn, tbq + l*Dn,
                                    tWk + l*Dn*Dn, tbk + l*Dn,
                                    tWv + l*Dn*Dn, tbv + l*Dn, q, k, v);
    k_attn<<<dim3(128,5,16), 128, 0, stream>>>(q, k, v, o, out_c + (size_t)l*16*5*128*128);
    k_oln_ffln<<<2048, 320, 0, stream>>>(o, tWo + l*Dn*Dn, tbo + l*Dn,
                                         tW1 + l*FFn*Dn, tb1 + l*FFn,
                                         tW2 + l*Dn*FFn, tb2 + l*Dn,
                                         tlng + l*Dn, tlnb + l*Dn, src);
  }
  k_gx8<80><<<dim3(256,2), 256, 0, stream>>>(src, l0fWih, l0fb, l0bWih, l0bb, gx);
  k_bilstm_rec5<<<dim3(16,2), 512, 0, stream>>>(gx, l0fWhh, l0bWhh, lout0);
  k_gx8<128><<<dim3(256,2), 256, 0, stream>>>(lout0, l1fWih, l1fb, l1bWih, l1bb, gx);
  k_bilstm_rec5<<<dim3(16,2), 512, 0, stream>>>(gx, l1fWhh, l1bWhh, lout1);
  k_final<<<16, 128, 0, stream>>>(lout1, fc1W, fc1b, fc2W, fc2b, outp);
}